// Round 1
// baseline (3195.292 us; speedup 1.0000x reference)
//
#include <hip/hip_runtime.h>
#include <math.h>

#define BATCH 2
#define SEQ 2048
#define NX 1024
#define NSTATE 1024
#define NHEAD 16
#define HDIM 64
// qkv row stride
#define QKV_LD (3*NSTATE)

// C[M,N] = A[M,K] @ W[K,N] + bias[N]; A,W,C row-major. BM=BN=64, BK=16, 256 thr.
__global__ __launch_bounds__(256) void gemm_bias_kernel(
    const float* __restrict__ A, const float* __restrict__ W,
    const float* __restrict__ bias, float* __restrict__ C,
    int M, int N, int K)
{
    const int BM = 64, BN = 64, BK = 16;
    __shared__ float As[16][64 + 1];   // [kk][row], padded
    __shared__ float Bs[16][64];       // [kk][col]

    const int tid = threadIdx.x;
    const int tx = tid % 16, ty = tid / 16;
    const int bm = blockIdx.x * BM;
    const int bn = blockIdx.y * BN;

    float acc[4][4] = {};

    for (int k0 = 0; k0 < K; k0 += BK) {
        // Load A tile: 64 rows x 16 cols, float4 per thread
        {
            int idx = tid * 4;
            int r = idx / BK;          // 0..63
            int c = idx % BK;          // 0,4,8,12
            float4 a4 = *(const float4*)&A[(size_t)(bm + r) * K + k0 + c];
            As[c + 0][r] = a4.x;
            As[c + 1][r] = a4.y;
            As[c + 2][r] = a4.z;
            As[c + 3][r] = a4.w;
        }
        // Load B tile: 16 rows x 64 cols, float4 per thread
        {
            int idx = tid * 4;
            int r = idx / BN;          // 0..15
            int c = idx % BN;          // 0,4,...,60
            float4 b4 = *(const float4*)&W[(size_t)(k0 + r) * N + bn + c];
            *(float4*)&Bs[r][c] = b4;
        }
        __syncthreads();

        #pragma unroll
        for (int kk = 0; kk < BK; kk++) {
            float a[4], b[4];
            #pragma unroll
            for (int i = 0; i < 4; i++) a[i] = As[kk][ty * 4 + i];
            #pragma unroll
            for (int j = 0; j < 4; j++) b[j] = Bs[kk][tx * 4 + j];
            #pragma unroll
            for (int i = 0; i < 4; i++)
                #pragma unroll
                for (int j = 0; j < 4; j++)
                    acc[i][j] += a[i] * b[j];
        }
        __syncthreads();
    }

    #pragma unroll
    for (int i = 0; i < 4; i++) {
        int r = bm + ty * 4 + i;
        #pragma unroll
        for (int j = 0; j < 4; j++) {
            int c = bn + tx * 4 + j;
            C[(size_t)r * N + c] = acc[i][j] + bias[c];
        }
    }
}

// Flash attention, fp32. One wave (64 thr) per block; each lane owns one q row.
// grid: (S/64, NHEAD, BATCH)
__global__ __launch_bounds__(64) void attn_kernel(
    const float* __restrict__ qkv, float* __restrict__ a_out)
{
    const int qt = blockIdx.x;
    const int h  = blockIdx.y;
    const int b  = blockIdx.z;
    const int t  = threadIdx.x;
    const int q  = qt * 64 + t;

    float qreg[HDIM];
    {
        const size_t rowQ = (size_t)(b * SEQ + q) * QKV_LD + h * HDIM;
        #pragma unroll
        for (int d = 0; d < HDIM; d++) qreg[d] = qkv[rowQ + d];
    }

    float acc[HDIM];
    #pragma unroll
    for (int d = 0; d < HDIM; d++) acc[d] = 0.f;
    float m = -1e30f, l = 0.f;

    __shared__ float Ks[32][HDIM];
    __shared__ float Vs[32][HDIM];

    const int ktiles = (qt + 1) * 2;   // causal: keys up to (qt+1)*64
    for (int kt = 0; kt < ktiles; kt++) {
        const int k0 = kt * 32;
        // cooperative K/V tile load, coalesced over t
        for (int i = 0; i < 32; i++) {
            const size_t row = (size_t)(b * SEQ + k0 + i) * QKV_LD;
            Ks[i][t] = qkv[row + NSTATE     + h * HDIM + t];
            Vs[i][t] = qkv[row + 2 * NSTATE + h * HDIM + t];
        }
        __syncthreads();

        float s[32];
        #pragma unroll
        for (int j = 0; j < 32; j++) {
            float sc = 0.f;
            #pragma unroll
            for (int d = 0; d < HDIM; d++) sc += qreg[d] * Ks[j][d];
            const int kk = k0 + j;
            s[j] = (kk <= q) ? sc * 0.125f : -1e9f;
        }

        float tm = m;
        #pragma unroll
        for (int j = 0; j < 32; j++) tm = fmaxf(tm, s[j]);
        const float alpha = __expf(m - tm);
        m = tm;
        l *= alpha;
        #pragma unroll
        for (int d = 0; d < HDIM; d++) acc[d] *= alpha;

        for (int j = 0; j < 32; j++) {
            const float p = __expf(s[j] - m);
            l += p;
            #pragma unroll
            for (int d = 0; d < HDIM; d++) acc[d] += p * Vs[j][d];
        }
        __syncthreads();
    }

    const float inv = 1.f / l;
    const size_t rowO = (size_t)(b * SEQ + q) * NSTATE + h * HDIM;
    #pragma unroll
    for (int d = 0; d < HDIM; d++) a_out[rowO + d] = acc[d] * inv;
}

extern "C" void kernel_launch(void* const* d_in, const int* in_sizes, int n_in,
                              void* d_out, int out_size, void* d_ws, size_t ws_size,
                              hipStream_t stream)
{
    const float* x   = (const float*)d_in[0];
    const float* w_c = (const float*)d_in[1];
    const float* b_c = (const float*)d_in[2];
    const float* w_p = (const float*)d_in[3];
    const float* b_p = (const float*)d_in[4];
    float* out = (float*)d_out;

    const int M = BATCH * SEQ;             // 4096
    float* qkv = (float*)d_ws;                                   // [M][3072]
    float* attn_out = qkv + (size_t)M * QKV_LD;                  // [M][1024]

    // 1) QKV projection: [4096,1024] x [1024,3072]
    {
        dim3 grid(M / 64, (3 * NSTATE) / 64);
        gemm_bias_kernel<<<grid, 256, 0, stream>>>(x, w_c, b_c, qkv,
                                                   M, 3 * NSTATE, NX);
    }
    // 2) causal flash attention -> attn_out [4096,1024]
    {
        dim3 grid(SEQ / 64, NHEAD, BATCH);
        attn_kernel<<<grid, 64, 0, stream>>>(qkv, attn_out);
    }
    // 3) output projection: [4096,1024] x [1024,1024]
    {
        dim3 grid(M / 64, NSTATE / 64);
        gemm_bias_kernel<<<grid, 256, 0, stream>>>(attn_out, w_p, b_p, out,
                                                   M, NSTATE, NX);
    }
}

// Round 2
// 1504.080 us; speedup vs baseline: 2.1244x; 2.1244x over previous
//
#include <hip/hip_runtime.h>
#include <math.h>

#define BATCH 2
#define SEQ 2048
#define NX 1024
#define NSTATE 1024
#define NHEAD 16
#define HDIM 64
#define QKV_LD (3*NSTATE)

typedef __attribute__((ext_vector_type(4))) float f32x4;
typedef __attribute__((ext_vector_type(8))) short bf16x8;

__device__ __forceinline__ unsigned short f2bf(float x) {
    unsigned int u = __float_as_uint(x);
    u = (u + 0x7FFFu + ((u >> 16) & 1u)) >> 16;
    return (unsigned short)u;
}

// elementwise fp32 -> bf16 (vectorized float4 -> ushort4)
__global__ __launch_bounds__(256) void cast_kernel(const float* __restrict__ in,
                                                   unsigned short* __restrict__ out,
                                                   int n4)
{
    int i = blockIdx.x * 256 + threadIdx.x;
    if (i >= n4) return;
    float4 v = ((const float4*)in)[i];
    ushort4 o;
    o.x = f2bf(v.x); o.y = f2bf(v.y); o.z = f2bf(v.z); o.w = f2bf(v.w);
    ((ushort4*)out)[i] = o;
}

// in fp32 [R][C] -> out bf16 [C][R]; R,C multiples of 64
__global__ __launch_bounds__(256) void transpose_cast_kernel(
    const float* __restrict__ in, unsigned short* __restrict__ out, int R, int C)
{
    __shared__ float tile[64][65];
    const int t = threadIdx.x;
    const int c0 = blockIdx.x * 64;   // C tile origin
    const int r0 = blockIdx.y * 64;   // R tile origin
    const int cc = t & 63;
    const int rb = t >> 6;
    #pragma unroll
    for (int i = 0; i < 16; i++) {
        int rr = rb + i * 4;
        tile[rr][cc] = in[(size_t)(r0 + rr) * C + c0 + cc];
    }
    __syncthreads();
    #pragma unroll
    for (int i = 0; i < 16; i++) {
        int rr = rb + i * 4;
        out[(size_t)(c0 + rr) * R + r0 + cc] = f2bf(tile[cc][rr]);
    }
}

// C[M,N] = A[M,K] (bf16) @ BT[N,K]^T (bf16) + bias, fp32 out.
// 128x128 tile, BK=32, 4 waves (2x2 of 64x64), mfma_f32_16x16x32_bf16.
__global__ __launch_bounds__(256) void gemm_bf16(
    const unsigned short* __restrict__ A,
    const unsigned short* __restrict__ BT,
    const float* __restrict__ bias,
    float* __restrict__ C, int M, int N, int K)
{
    __shared__ unsigned short Als[128 * 32];
    __shared__ unsigned short Bls[128 * 32];
    const int tid = threadIdx.x;
    const int wave = tid >> 6, lane = tid & 63;
    const int bm = blockIdx.x * 128, bn = blockIdx.y * 128;
    const int wr = (wave >> 1) * 64, wc = (wave & 1) * 64;

    f32x4 acc[4][4];
    #pragma unroll
    for (int m = 0; m < 4; m++)
        #pragma unroll
        for (int n = 0; n < 4; n++)
            acc[m][n] = (f32x4){0.f, 0.f, 0.f, 0.f};

    const int arow = tid >> 2;         // 0..63
    const int ac8 = (tid & 3) * 8;     // k element offset (8 bf16 = 16B)
    char* alds0 = (char*)Als + wave * 1024;
    char* blds0 = (char*)Bls + wave * 1024;

    const int fr = lane & 15, kq = (lane >> 4) * 8;

    for (int k0 = 0; k0 < K; k0 += 32) {
        const unsigned short* ga0 = A  + (size_t)(bm + arow) * K + k0 + ac8;
        const unsigned short* gb0 = BT + (size_t)(bn + arow) * K + k0 + ac8;
        __builtin_amdgcn_global_load_lds(
            (const __attribute__((address_space(1))) void*)ga0,
            (__attribute__((address_space(3))) void*)alds0, 16, 0, 0);
        __builtin_amdgcn_global_load_lds(
            (const __attribute__((address_space(1))) void*)(ga0 + (size_t)64 * K),
            (__attribute__((address_space(3))) void*)(alds0 + 4096), 16, 0, 0);
        __builtin_amdgcn_global_load_lds(
            (const __attribute__((address_space(1))) void*)gb0,
            (__attribute__((address_space(3))) void*)blds0, 16, 0, 0);
        __builtin_amdgcn_global_load_lds(
            (const __attribute__((address_space(1))) void*)(gb0 + (size_t)64 * K),
            (__attribute__((address_space(3))) void*)(blds0 + 4096), 16, 0, 0);
        __syncthreads();

        bf16x8 af[4], bfr[4];
        #pragma unroll
        for (int m = 0; m < 4; m++)
            af[m] = *(const bf16x8*)&Als[(wr + m * 16 + fr) * 32 + kq];
        #pragma unroll
        for (int n = 0; n < 4; n++)
            bfr[n] = *(const bf16x8*)&Bls[(wc + n * 16 + fr) * 32 + kq];
        #pragma unroll
        for (int m = 0; m < 4; m++)
            #pragma unroll
            for (int n = 0; n < 4; n++)
                acc[m][n] = __builtin_amdgcn_mfma_f32_16x16x32_bf16(
                    af[m], bfr[n], acc[m][n], 0, 0, 0);
        __syncthreads();
    }

    const int cr = (lane >> 4) * 4;
    const int ccol = lane & 15;
    #pragma unroll
    for (int m = 0; m < 4; m++) {
        const int row = bm + wr + m * 16 + cr;
        #pragma unroll
        for (int n = 0; n < 4; n++) {
            const int col = bn + wc + n * 16 + ccol;
            const float bv = bias[col];
            #pragma unroll
            for (int j = 0; j < 4; j++)
                C[(size_t)(row + j) * N + col] = acc[m][n][j] + bv;
        }
    }
}

// Flash attention fp32. 1 wave per block; 16 q-rows/wave, 4 lanes per row
// splitting D=64 into 4x16. Writes bf16 output. grid: (S/16, H, B)
__global__ __launch_bounds__(64) void attn_kernel(
    const float* __restrict__ qkv, unsigned short* __restrict__ a_out)
{
    const int qt = blockIdx.x;
    const int h = blockIdx.y, b = blockIdx.z;
    const int t = threadIdx.x;
    const int r = t >> 2, g = t & 3;
    const int q = qt * 16 + r;

    __shared__ float Ks[32][64];
    __shared__ float Vs[32][64];

    f32x4 qv[4];
    {
        const float* qp = qkv + (size_t)(b * SEQ + q) * QKV_LD + h * HDIM + g * 16;
        #pragma unroll
        for (int i = 0; i < 4; i++) {
            f32x4 v = *(const f32x4*)(qp + i * 4);
            qv[i] = v * 0.125f;   // rsqrt(64) folded into Q
        }
    }

    f32x4 acc[4];
    #pragma unroll
    for (int i = 0; i < 4; i++) acc[i] = (f32x4){0.f, 0.f, 0.f, 0.f};
    float m = -1e30f, l = 0.f;

    const int nkt = qt / 2 + 1;
    for (int kt = 0; kt < nkt; kt++) {
        const int k0 = kt * 32;
        #pragma unroll
        for (int i = 0; i < 8; i++) {
            int f4 = t + i * 64;
            int row = f4 >> 4, c4 = (f4 & 15) * 4;
            const float* src = qkv + (size_t)(b * SEQ + k0 + row) * QKV_LD
                               + NSTATE + h * HDIM + c4;
            *(f32x4*)&Ks[row][c4] = *(const f32x4*)src;
            *(f32x4*)&Vs[row][c4] = *(const f32x4*)(src + NSTATE);
        }
        __syncthreads();

        float s[32];
        #pragma unroll
        for (int j = 0; j < 32; j++) {
            const f32x4* kr = (const f32x4*)&Ks[j][g * 16];
            f32x4 p4 = qv[0] * kr[0];
            p4 += qv[1] * kr[1];
            p4 += qv[2] * kr[2];
            p4 += qv[3] * kr[3];
            float p = p4.x + p4.y + p4.z + p4.w;
            p += __shfl_xor(p, 1);
            p += __shfl_xor(p, 2);
            s[j] = (k0 + j <= q) ? p : -1e9f;
        }
        float tm = m;
        #pragma unroll
        for (int j = 0; j < 32; j++) tm = fmaxf(tm, s[j]);
        const float alpha = __expf(m - tm);
        m = tm;
        l *= alpha;
        #pragma unroll
        for (int i = 0; i < 4; i++) acc[i] *= alpha;
        #pragma unroll
        for (int j = 0; j < 32; j++) {
            const float p = __expf(s[j] - m);
            l += p;
            const f32x4* vr = (const f32x4*)&Vs[j][g * 16];
            acc[0] += p * vr[0];
            acc[1] += p * vr[1];
            acc[2] += p * vr[2];
            acc[3] += p * vr[3];
        }
        __syncthreads();
    }

    const float inv = 1.f / l;
    unsigned short o[16];
    #pragma unroll
    for (int i = 0; i < 4; i++) {
        f32x4 v = acc[i] * inv;
        o[i * 4 + 0] = f2bf(v.x); o[i * 4 + 1] = f2bf(v.y);
        o[i * 4 + 2] = f2bf(v.z); o[i * 4 + 3] = f2bf(v.w);
    }
    unsigned short* op = a_out + (size_t)(b * SEQ + q) * NSTATE + h * HDIM + g * 16;
    ((f32x4*)op)[0] = ((const f32x4*)o)[0];
    ((f32x4*)op)[1] = ((const f32x4*)o)[1];
}

extern "C" void kernel_launch(void* const* d_in, const int* in_sizes, int n_in,
                              void* d_out, int out_size, void* d_ws, size_t ws_size,
                              hipStream_t stream)
{
    const float* x   = (const float*)d_in[0];
    const float* w_c = (const float*)d_in[1];
    const float* b_c = (const float*)d_in[2];
    const float* w_p = (const float*)d_in[3];
    const float* b_p = (const float*)d_in[4];
    float* out = (float*)d_out;

    const int M = BATCH * SEQ;   // 4096

    char* ws = (char*)d_ws;
    float* qkv = (float*)ws;                                              // 50331648 B
    unsigned short* xbf = (unsigned short*)(ws + 50331648);               // 8388608 B (reused as attn_out)
    unsigned short* wcT = (unsigned short*)(ws + 50331648 + 8388608);     // 6291456 B
    unsigned short* wpT = (unsigned short*)(ws + 50331648 + 8388608 + 6291456); // 2097152 B

    // casts / transposes (one-time per call)
    cast_kernel<<<(M * NX / 4 + 255) / 256, 256, 0, stream>>>(x, xbf, M * NX / 4);
    transpose_cast_kernel<<<dim3(3 * NSTATE / 64, NX / 64), 256, 0, stream>>>(
        w_c, wcT, NX, 3 * NSTATE);
    transpose_cast_kernel<<<dim3(NSTATE / 64, NX / 64), 256, 0, stream>>>(
        w_p, wpT, NX, NSTATE);

    // 1) QKV projection: [4096,1024]x[1024,3072] -> fp32 qkv
    gemm_bf16<<<dim3(M / 128, 3 * NSTATE / 128), 256, 0, stream>>>(
        xbf, wcT, b_c, qkv, M, 3 * NSTATE, NX);

    // 2) causal flash attention -> bf16 attn_out (reuses xbf buffer)
    attn_kernel<<<dim3(SEQ / 16, NHEAD, BATCH), 64, 0, stream>>>(qkv, xbf);

    // 3) output projection: [4096,1024]x[1024,1024] -> d_out fp32
    gemm_bf16<<<dim3(M / 128, NSTATE / 128), 256, 0, stream>>>(
        xbf, wpT, b_p, out, M, NSTATE, NX);
}

// Round 3
// 250.108 us; speedup vs baseline: 12.7757x; 6.0137x over previous
//
#include <hip/hip_runtime.h>
#include <math.h>

#define BATCH 2
#define SEQ 2048
#define NX 1024
#define NSTATE 1024
#define NHEAD 16
#define HDIM 64
#define QKV_LD (3*NSTATE)

typedef __attribute__((ext_vector_type(4))) float f32x4;
typedef __attribute__((ext_vector_type(8))) short bf16x8;

__device__ __forceinline__ unsigned short f2bf(float x) {
    unsigned int u = __float_as_uint(x);
    u = (u + 0x7FFFu + ((u >> 16) & 1u)) >> 16;
    return (unsigned short)u;
}

#define GLL(src, dst) __builtin_amdgcn_global_load_lds( \
    (const __attribute__((address_space(1))) void*)(src), \
    (__attribute__((address_space(3))) void*)(dst), 16, 0, 0)

// elementwise fp32 -> bf16
__global__ __launch_bounds__(256) void cast_kernel(const float* __restrict__ in,
                                                   unsigned short* __restrict__ out,
                                                   int n4)
{
    int i = blockIdx.x * 256 + threadIdx.x;
    if (i >= n4) return;
    float4 v = ((const float4*)in)[i];
    ushort4 o;
    o.x = f2bf(v.x); o.y = f2bf(v.y); o.z = f2bf(v.z); o.w = f2bf(v.w);
    ((ushort4*)out)[i] = o;
}

// in fp32 [R][C] -> out bf16 [C][R]
__global__ __launch_bounds__(256) void transpose_cast_kernel(
    const float* __restrict__ in, unsigned short* __restrict__ out, int R, int C)
{
    __shared__ float tile[64][65];
    const int t = threadIdx.x;
    const int c0 = blockIdx.x * 64;
    const int r0 = blockIdx.y * 64;
    const int cc = t & 63;
    const int rb = t >> 6;
    #pragma unroll
    for (int i = 0; i < 16; i++) {
        int rr = rb + i * 4;
        tile[rr][cc] = in[(size_t)(r0 + rr) * C + c0 + cc];
    }
    __syncthreads();
    #pragma unroll
    for (int i = 0; i < 16; i++) {
        int rr = rb + i * 4;
        out[(size_t)(c0 + rr) * R + r0 + cc] = f2bf(tile[cc][rr]);
    }
}

// V-part of qkv (bf16) -> vt[(b*16+h)*64+d][s]  (bf16)
__global__ __launch_bounds__(256) void vtrans_kernel(
    const unsigned short* __restrict__ qkv, unsigned short* __restrict__ vt)
{
    __shared__ unsigned short t[64][72];
    const int s0 = blockIdx.x * 64;
    const int bh = blockIdx.y;
    const int b = bh >> 4, h = bh & 15;
    const int r = threadIdx.x >> 2;
    const int cg = (threadIdx.x & 3) * 16;
    const unsigned short* src = qkv + (size_t)(b * SEQ + s0 + r) * QKV_LD
                                + 2 * NSTATE + h * HDIM + cg;
    *(bf16x8*)&t[r][cg]     = *(const bf16x8*)src;
    *(bf16x8*)&t[r][cg + 8] = *(const bf16x8*)(src + 8);
    __syncthreads();
    unsigned short tmp[16];
    #pragma unroll
    for (int i = 0; i < 16; i++) tmp[i] = t[cg + i][r];
    unsigned short* dst = vt + (size_t)(bh * 64 + r) * SEQ + s0 + cg;
    *(bf16x8*)dst       = ((const bf16x8*)tmp)[0];
    *(bf16x8*)(dst + 8) = ((const bf16x8*)tmp)[1];
}

// C[M,N] = A[M,K](bf16) @ BT[N,K]^T(bf16) + bias; out fp32 or bf16.
template<bool BF16_OUT>
__global__ __launch_bounds__(256) void gemm_bf16(
    const unsigned short* __restrict__ A,
    const unsigned short* __restrict__ BT,
    const float* __restrict__ bias,
    void* __restrict__ Cv, int M, int N, int K)
{
    __shared__ unsigned short Als[128 * 32];
    __shared__ unsigned short Bls[128 * 32];
    const int tid = threadIdx.x;
    const int wave = tid >> 6, lane = tid & 63;
    const int bm = blockIdx.x * 128, bn = blockIdx.y * 128;
    const int wr = (wave >> 1) * 64, wc = (wave & 1) * 64;

    f32x4 acc[4][4];
    #pragma unroll
    for (int m = 0; m < 4; m++)
        #pragma unroll
        for (int n = 0; n < 4; n++)
            acc[m][n] = (f32x4){0.f, 0.f, 0.f, 0.f};

    const int arow = tid >> 2;
    const int ac8 = (tid & 3) * 8;
    char* alds0 = (char*)Als + wave * 1024;
    char* blds0 = (char*)Bls + wave * 1024;
    const int fr = lane & 15, kq = (lane >> 4) * 8;

    for (int k0 = 0; k0 < K; k0 += 32) {
        const unsigned short* ga0 = A  + (size_t)(bm + arow) * K + k0 + ac8;
        const unsigned short* gb0 = BT + (size_t)(bn + arow) * K + k0 + ac8;
        GLL(ga0, alds0);
        GLL(ga0 + (size_t)64 * K, alds0 + 4096);
        GLL(gb0, blds0);
        GLL(gb0 + (size_t)64 * K, blds0 + 4096);
        __syncthreads();

        bf16x8 af[4], bfr[4];
        #pragma unroll
        for (int m = 0; m < 4; m++)
            af[m] = *(const bf16x8*)&Als[(wr + m * 16 + fr) * 32 + kq];
        #pragma unroll
        for (int n = 0; n < 4; n++)
            bfr[n] = *(const bf16x8*)&Bls[(wc + n * 16 + fr) * 32 + kq];
        #pragma unroll
        for (int m = 0; m < 4; m++)
            #pragma unroll
            for (int n = 0; n < 4; n++)
                acc[m][n] = __builtin_amdgcn_mfma_f32_16x16x32_bf16(
                    af[m], bfr[n], acc[m][n], 0, 0, 0);
        __syncthreads();
    }

    const int cr = (lane >> 4) * 4;
    const int ccol = lane & 15;
    #pragma unroll
    for (int m = 0; m < 4; m++) {
        const int row = bm + wr + m * 16 + cr;
        #pragma unroll
        for (int n = 0; n < 4; n++) {
            const int col = bn + wc + n * 16 + ccol;
            const float bv = bias[col];
            #pragma unroll
            for (int j = 0; j < 4; j++) {
                float v = acc[m][n][j] + bv;
                if (BF16_OUT)
                    ((unsigned short*)Cv)[(size_t)(row + j) * N + col] = f2bf(v);
                else
                    ((float*)Cv)[(size_t)(row + j) * N + col] = v;
            }
        }
    }
}

// MFMA flash attention. 4 waves x 16 q-rows; KV tiles of 64.
// Swapped QK^T (mfma(K,Q)) -> lane-local softmax rows. grid (S/64, H, B).
__global__ __launch_bounds__(256) void attn_mfma(
    const unsigned short* __restrict__ qkv,
    const unsigned short* __restrict__ vt,
    unsigned short* __restrict__ a_out)
{
    const int qb = (int)gridDim.x - 1 - (int)blockIdx.x;   // long blocks first
    const int h = blockIdx.y, b = blockIdx.z;
    const int tid = threadIdx.x;
    const int w = tid >> 6, lane = tid & 63;
    const int c = lane & 15, hh = lane >> 4;

    __shared__ unsigned short Kls[64 * 64];
    __shared__ unsigned short Vls[64 * 64];
    __shared__ unsigned short Pls[4][16 * 64];

    // Q fragments (B-operand): lane reads Q[q=c][d = s*32 + hh*8 ..+7]
    const size_t qrow = (size_t)(b * SEQ + qb * 64 + w * 16 + c);
    const unsigned short* qp = qkv + qrow * QKV_LD + h * HDIM;
    bf16x8 qf0 = *(const bf16x8*)(qp + hh * 8);
    bf16x8 qf1 = *(const bf16x8*)(qp + 32 + hh * 8);

    f32x4 acc_o[4];
    #pragma unroll
    for (int n = 0; n < 4; n++) acc_o[n] = (f32x4){0.f, 0.f, 0.f, 0.f};
    float m_run = -1e30f, l = 0.f;

    // staging geometry: LDS byte o = tid*16 (+4096); row r = o>>7; swizzled src col
    const int o0 = tid * 16;
    const int r0 = o0 >> 7, sc0 = (o0 & 127) ^ ((r0 & 7) << 4);
    const int o1 = 4096 + tid * 16;
    const int r1 = o1 >> 7, sc1 = (o1 & 127) ^ ((r1 & 7) << 4);

    char* kld = (char*)Kls + w * 1024;
    char* vld = (char*)Vls + w * 1024;
    const char* gkbase = (const char*)(qkv + (size_t)b * SEQ * QKV_LD + NSTATE + h * HDIM);
    const char* gvbase = (const char*)(vt + (size_t)(b * NHEAD + h) * HDIM * SEQ);

    const int nkt = qb + 1;
    for (int kt = 0; kt < nkt; kt++) {
        __syncthreads();   // protect LDS from previous iteration's readers
        {
            const char* gk = gkbase + (size_t)kt * 64 * 6144;
            const char* gv = gvbase + (size_t)kt * 128;
            GLL(gk + (size_t)r0 * 6144 + sc0, kld);
            GLL(gk + (size_t)r1 * 6144 + sc1, kld + 4096);
            GLL(gv + (size_t)r0 * 4096 + sc0, vld);
            GLL(gv + (size_t)r1 * 4096 + sc1, vld + 4096);
        }
        __syncthreads();

        // QK^T (swapped): sacc[m] cols=q, rows=keys m*16 + hh*4 + j
        f32x4 sacc[4];
        #pragma unroll
        for (int m = 0; m < 4; m++) {
            const int row = m * 16 + c;
            const int sw = (row & 7) << 4;
            bf16x8 kf0 = *(const bf16x8*)((const char*)Kls + row * 128 + ((hh * 16) ^ sw));
            bf16x8 kf1 = *(const bf16x8*)((const char*)Kls + row * 128 + ((64 + hh * 16) ^ sw));
            f32x4 z = (f32x4){0.f, 0.f, 0.f, 0.f};
            z = __builtin_amdgcn_mfma_f32_16x16x32_bf16(kf0, qf0, z, 0, 0, 0);
            sacc[m] = __builtin_amdgcn_mfma_f32_16x16x32_bf16(kf1, qf1, z, 0, 0, 0);
        }

        // softmax (scores for q-row c live in this lane + lanes c+16k)
        const bool diag = (kt == qb);
        float s[16];
        float tmax = m_run;
        #pragma unroll
        for (int m = 0; m < 4; m++)
            #pragma unroll
            for (int j = 0; j < 4; j++) {
                float sv = sacc[m][j] * 0.125f;
                if (diag) {
                    int klocal = m * 16 + hh * 4 + j;
                    if (klocal > w * 16 + c) sv = -1e30f;
                }
                s[m * 4 + j] = sv;
                tmax = fmaxf(tmax, sv);
            }
        tmax = fmaxf(tmax, __shfl_xor(tmax, 16));
        tmax = fmaxf(tmax, __shfl_xor(tmax, 32));
        const float alpha = __expf(m_run - tmax);
        m_run = tmax;
        l *= alpha;
        float p[16];
        #pragma unroll
        for (int i = 0; i < 16; i++) {
            p[i] = __expf(s[i] - m_run);
            l += p[i];
        }

        // pack P -> bf16, write to per-wave swizzled LDS
        {
            char* pb = (char*)&Pls[w][0] + c * 128;
            const int swp = (c & 7) << 4;
            #pragma unroll
            for (int m = 0; m < 4; m++) {
                unsigned int lo = (unsigned int)f2bf(p[m * 4 + 0]) |
                                  ((unsigned int)f2bf(p[m * 4 + 1]) << 16);
                unsigned int hi = (unsigned int)f2bf(p[m * 4 + 2]) |
                                  ((unsigned int)f2bf(p[m * 4 + 3]) << 16);
                uint2 u; u.x = lo; u.y = hi;
                *(uint2*)(pb + ((m * 32 + hh * 8) ^ swp)) = u;
            }
        }

        // rescale acc_o by per-row alpha (rows hh*4+j)
        {
            float a0 = __shfl(alpha, hh * 4 + 0);
            float a1 = __shfl(alpha, hh * 4 + 1);
            float a2 = __shfl(alpha, hh * 4 + 2);
            float a3 = __shfl(alpha, hh * 4 + 3);
            #pragma unroll
            for (int n = 0; n < 4; n++) {
                acc_o[n][0] *= a0; acc_o[n][1] *= a1;
                acc_o[n][2] *= a2; acc_o[n][3] *= a3;
            }
        }

        // PV: out[q][d], A = P, B = Vt
        {
            const char* pb = (const char*)&Pls[w][0] + c * 128;
            const int swp = (c & 7) << 4;
            bf16x8 pf0 = *(const bf16x8*)(pb + ((hh * 16) ^ swp));
            bf16x8 pf1 = *(const bf16x8*)(pb + ((64 + hh * 16) ^ swp));
            #pragma unroll
            for (int n = 0; n < 4; n++) {
                const int row = n * 16 + c;
                const int sw = (row & 7) << 4;
                bf16x8 vf0 = *(const bf16x8*)((const char*)Vls + row * 128 + ((hh * 16) ^ sw));
                bf16x8 vf1 = *(const bf16x8*)((const char*)Vls + row * 128 + ((64 + hh * 16) ^ sw));
                acc_o[n] = __builtin_amdgcn_mfma_f32_16x16x32_bf16(pf0, vf0, acc_o[n], 0, 0, 0);
                acc_o[n] = __builtin_amdgcn_mfma_f32_16x16x32_bf16(pf1, vf1, acc_o[n], 0, 0, 0);
            }
        }
    }

    // final normalization + store
    l += __shfl_xor(l, 16);
    l += __shfl_xor(l, 32);
    const float linv = 1.f / l;
    const float li0 = __shfl(linv, hh * 4 + 0);
    const float li1 = __shfl(linv, hh * 4 + 1);
    const float li2 = __shfl(linv, hh * 4 + 2);
    const float li3 = __shfl(linv, hh * 4 + 3);
    const size_t orow0 = (size_t)(b * SEQ + qb * 64 + w * 16 + hh * 4);
    #pragma unroll
    for (int n = 0; n < 4; n++) {
        const int col = h * HDIM + n * 16 + c;
        a_out[(orow0 + 0) * NSTATE + col] = f2bf(acc_o[n][0] * li0);
        a_out[(orow0 + 1) * NSTATE + col] = f2bf(acc_o[n][1] * li1);
        a_out[(orow0 + 2) * NSTATE + col] = f2bf(acc_o[n][2] * li2);
        a_out[(orow0 + 3) * NSTATE + col] = f2bf(acc_o[n][3] * li3);
    }
}

extern "C" void kernel_launch(void* const* d_in, const int* in_sizes, int n_in,
                              void* d_out, int out_size, void* d_ws, size_t ws_size,
                              hipStream_t stream)
{
    const float* x   = (const float*)d_in[0];
    const float* w_c = (const float*)d_in[1];
    const float* b_c = (const float*)d_in[2];
    const float* w_p = (const float*)d_in[3];
    const float* b_p = (const float*)d_in[4];
    float* out = (float*)d_out;

    const int M = BATCH * SEQ;   // 4096

    char* ws = (char*)d_ws;
    unsigned short* qkvbf = (unsigned short*)ws;                          // 25165824 B
    unsigned short* vt    = (unsigned short*)(ws + 25165824);             //  8388608 B
    unsigned short* xbf   = (unsigned short*)(ws + 25165824 + 8388608);   //  8388608 B (reused as attn_out)
    unsigned short* wcT   = (unsigned short*)(ws + 25165824 + 2*8388608); //  6291456 B
    unsigned short* wpT   = (unsigned short*)(ws + 25165824 + 2*8388608 + 6291456); // 2097152 B

    cast_kernel<<<(M * NX / 4 + 255) / 256, 256, 0, stream>>>(x, xbf, M * NX / 4);
    transpose_cast_kernel<<<dim3(3 * NSTATE / 64, NX / 64), 256, 0, stream>>>(
        w_c, wcT, NX, 3 * NSTATE);
    transpose_cast_kernel<<<dim3(NSTATE / 64, NX / 64), 256, 0, stream>>>(
        w_p, wpT, NX, NSTATE);

    // 1) QKV projection -> bf16 qkv
    gemm_bf16<true><<<dim3(M / 128, 3 * NSTATE / 128), 256, 0, stream>>>(
        xbf, wcT, b_c, qkvbf, M, 3 * NSTATE, NX);

    // 1b) transpose V -> vt
    vtrans_kernel<<<dim3(SEQ / 64, BATCH * NHEAD), 256, 0, stream>>>(qkvbf, vt);

    // 2) MFMA flash attention -> bf16 attn_out (reuses xbf)
    attn_mfma<<<dim3(SEQ / 64, NHEAD, BATCH), 256, 0, stream>>>(qkvbf, vt, xbf);

    // 3) output projection -> fp32 d_out
    gemm_bf16<false><<<dim3(M / 128, NSTATE / 128), 256, 0, stream>>>(
        xbf, wpT, b_p, out, M, NSTATE, NX);
}

// Round 5
// 232.885 us; speedup vs baseline: 13.7205x; 1.0740x over previous
//
#include <hip/hip_runtime.h>
#include <math.h>

#define BATCH 2
#define SEQ 2048
#define NX 1024
#define NSTATE 1024
#define NHEAD 16
#define HDIM 64
#define QKV_LD (3*NSTATE)

typedef __attribute__((ext_vector_type(4))) float f32x4;
typedef __attribute__((ext_vector_type(8))) short bf16x8;

__device__ __forceinline__ unsigned short f2bf(float x) {
    unsigned int u = __float_as_uint(x);
    u = (u + 0x7FFFu + ((u >> 16) & 1u)) >> 16;
    return (unsigned short)u;
}

#define GLL(src, dst) __builtin_amdgcn_global_load_lds( \
    (const __attribute__((address_space(1))) void*)(src), \
    (__attribute__((address_space(3))) void*)(dst), 16, 0, 0)

// Fused prep: [0,4096) cast x -> bf16; [4096,4864) transpose-cast w_c;
// [4864,5120) transpose-cast w_p.
__global__ __launch_bounds__(256) void prep_kernel(
    const float* __restrict__ x, const float* __restrict__ w_c,
    const float* __restrict__ w_p,
    unsigned short* __restrict__ xbf, unsigned short* __restrict__ wcT,
    unsigned short* __restrict__ wpT)
{
    const int bx = blockIdx.x;
    const int t = threadIdx.x;
    if (bx < 4096) {
        int i = bx * 256 + t;
        float4 v = ((const float4*)x)[i];
        ushort4 o;
        o.x = f2bf(v.x); o.y = f2bf(v.y); o.z = f2bf(v.z); o.w = f2bf(v.w);
        ((ushort4*)xbf)[i] = o;
        return;
    }
    __shared__ float tile[64][65];
    const float* in;
    unsigned short* out;
    int R, C, c0, r0;
    if (bx < 4096 + 768) {
        int idx = bx - 4096;
        in = w_c; out = wcT; R = NX; C = 3 * NSTATE;
        c0 = (idx % 48) * 64; r0 = (idx / 48) * 64;
    } else {
        int idx = bx - 4864;
        in = w_p; out = wpT; R = NX; C = NSTATE;
        c0 = (idx % 16) * 64; r0 = (idx / 16) * 64;
    }
    const int cc = t & 63;
    const int rb = t >> 6;
    #pragma unroll
    for (int i = 0; i < 16; i++) {
        int rr = rb + i * 4;
        tile[rr][cc] = in[(size_t)(r0 + rr) * C + c0 + cc];
    }
    __syncthreads();
    #pragma unroll
    for (int i = 0; i < 16; i++) {
        int rr = rb + i * 4;
        out[(size_t)(c0 + rr) * R + r0 + cc] = f2bf(tile[cc][rr]);
    }
}

// V-part of qkv (bf16) -> vt[(b*16+h)*64+d][s]  (bf16)
__global__ __launch_bounds__(256) void vtrans_kernel(
    const unsigned short* __restrict__ qkv, unsigned short* __restrict__ vt)
{
    __shared__ unsigned short t[64][72];
    const int s0 = blockIdx.x * 64;
    const int bh = blockIdx.y;
    const int b = bh >> 4, h = bh & 15;
    const int r = threadIdx.x >> 2;
    const int cg = (threadIdx.x & 3) * 16;
    const unsigned short* src = qkv + (size_t)(b * SEQ + s0 + r) * QKV_LD
                                + 2 * NSTATE + h * HDIM + cg;
    *(bf16x8*)&t[r][cg]     = *(const bf16x8*)src;
    *(bf16x8*)&t[r][cg + 8] = *(const bf16x8*)(src + 8);
    __syncthreads();
    unsigned short tmp[16];
    #pragma unroll
    for (int i = 0; i < 16; i++) tmp[i] = t[cg + i][r];
    unsigned short* dst = vt + (size_t)(bh * 64 + r) * SEQ + s0 + cg;
    *(bf16x8*)dst       = ((const bf16x8*)tmp)[0];
    *(bf16x8*)(dst + 8) = ((const bf16x8*)tmp)[1];
}

// C[M,N] = A[M,K](bf16) @ BT[N,K]^T(bf16) + bias; out fp32 or bf16.
template<bool BF16_OUT>
__global__ __launch_bounds__(256) void gemm_bf16(
    const unsigned short* __restrict__ A,
    const unsigned short* __restrict__ BT,
    const float* __restrict__ bias,
    void* __restrict__ Cv, int M, int N, int K)
{
    __shared__ unsigned short Als[128 * 32];
    __shared__ unsigned short Bls[128 * 32];
    const int tid = threadIdx.x;
    const int wave = tid >> 6, lane = tid & 63;
    const int bm = blockIdx.x * 128, bn = blockIdx.y * 128;
    const int wr = (wave >> 1) * 64, wc = (wave & 1) * 64;

    f32x4 acc[4][4];
    #pragma unroll
    for (int m = 0; m < 4; m++)
        #pragma unroll
        for (int n = 0; n < 4; n++)
            acc[m][n] = (f32x4){0.f, 0.f, 0.f, 0.f};

    const int arow = tid >> 2;
    const int ac8 = (tid & 3) * 8;
    char* alds0 = (char*)Als + wave * 1024;
    char* blds0 = (char*)Bls + wave * 1024;
    const int fr = lane & 15, kq = (lane >> 4) * 8;

    for (int k0 = 0; k0 < K; k0 += 32) {
        const unsigned short* ga0 = A  + (size_t)(bm + arow) * K + k0 + ac8;
        const unsigned short* gb0 = BT + (size_t)(bn + arow) * K + k0 + ac8;
        GLL(ga0, alds0);
        GLL(ga0 + (size_t)64 * K, alds0 + 4096);
        GLL(gb0, blds0);
        GLL(gb0 + (size_t)64 * K, blds0 + 4096);
        __syncthreads();

        bf16x8 af[4], bfr[4];
        #pragma unroll
        for (int m = 0; m < 4; m++)
            af[m] = *(const bf16x8*)&Als[(wr + m * 16 + fr) * 32 + kq];
        #pragma unroll
        for (int n = 0; n < 4; n++)
            bfr[n] = *(const bf16x8*)&Bls[(wc + n * 16 + fr) * 32 + kq];
        #pragma unroll
        for (int m = 0; m < 4; m++)
            #pragma unroll
            for (int n = 0; n < 4; n++)
                acc[m][n] = __builtin_amdgcn_mfma_f32_16x16x32_bf16(
                    af[m], bfr[n], acc[m][n], 0, 0, 0);
        __syncthreads();
    }

    const int cr = (lane >> 4) * 4;
    const int ccol = lane & 15;
    #pragma unroll
    for (int m = 0; m < 4; m++) {
        const int row = bm + wr + m * 16 + cr;
        #pragma unroll
        for (int n = 0; n < 4; n++) {
            const int col = bn + wc + n * 16 + ccol;
            const float bv = bias[col];
            #pragma unroll
            for (int j = 0; j < 4; j++) {
                float v = acc[m][n][j] + bv;
                if (BF16_OUT)
                    ((unsigned short*)Cv)[(size_t)(row + j) * N + col] = f2bf(v);
                else
                    ((float*)Cv)[(size_t)(row + j) * N + col] = v;
            }
        }
    }
}

// MFMA flash attention, double-buffered K/V staging (one barrier/tile).
// 4 waves x 16 q-rows; KV tiles of 64. Swapped QK^T. grid (S/64, H, B).
__global__ __launch_bounds__(256) void attn_mfma(
    const unsigned short* __restrict__ qkv,
    const unsigned short* __restrict__ vt,
    unsigned short* __restrict__ a_out)
{
    const int qb = (int)gridDim.x - 1 - (int)blockIdx.x;   // long blocks first
    const int h = blockIdx.y, b = blockIdx.z;
    const int tid = threadIdx.x;
    const int w = tid >> 6, lane = tid & 63;
    const int c = lane & 15, hh = lane >> 4;

    __shared__ unsigned short Kls[2 * 64 * 64];
    __shared__ unsigned short Vls[2 * 64 * 64];
    __shared__ unsigned short Pls[4][16 * 64];

    const size_t qrow = (size_t)(b * SEQ + qb * 64 + w * 16 + c);
    const unsigned short* qp = qkv + qrow * QKV_LD + h * HDIM;
    bf16x8 qf0 = *(const bf16x8*)(qp + hh * 8);
    bf16x8 qf1 = *(const bf16x8*)(qp + 32 + hh * 8);

    f32x4 acc_o[4];
    #pragma unroll
    for (int n = 0; n < 4; n++) acc_o[n] = (f32x4){0.f, 0.f, 0.f, 0.f};
    float m_run = -1e30f, l = 0.f;
    const float Cc = 0.18033688f;          // 0.125 * log2(e)

    // staging geometry: LDS byte o = tid*16 (+4096); row r = o>>7; swizzled src col
    const int o0 = tid * 16;
    const int r0 = o0 >> 7, sc0 = (o0 & 127) ^ ((r0 & 7) << 4);
    const int o1 = 4096 + tid * 16;
    const int r1 = o1 >> 7, sc1 = (o1 & 127) ^ ((r1 & 7) << 4);

    char* kld = (char*)Kls + w * 1024;
    char* vld = (char*)Vls + w * 1024;
    const char* gkbase = (const char*)(qkv + (size_t)b * SEQ * QKV_LD + NSTATE + h * HDIM);
    const char* gvbase = (const char*)(vt + (size_t)(b * NHEAD + h) * HDIM * SEQ);

    #define STAGE(kt_, buf_) do { \
        const char* gk = gkbase + (size_t)(kt_) * 64 * 6144; \
        const char* gv = gvbase + (size_t)(kt_) * 128; \
        char* kd = kld + (buf_) * 8192; \
        char* vd = vld + (buf_) * 8192; \
        GLL(gk + (size_t)r0 * 6144 + sc0, kd); \
        GLL(gk + (size_t)r1 * 6144 + sc1, kd + 4096); \
        GLL(gv + (size_t)r0 * 4096 + sc0, vd); \
        GLL(gv + (size_t)r1 * 4096 + sc1, vd + 4096); \
    } while (0)

    const int nkt = qb + 1;
    STAGE(0, 0);
    __syncthreads();

    for (int kt = 0; kt < nkt; kt++) {
        const int cur = kt & 1;
        if (kt + 1 < nkt) STAGE(kt + 1, cur ^ 1);

        const char* kb = (const char*)Kls + cur * 8192;
        const char* vb = (const char*)Vls + cur * 8192;

        // QK^T (swapped): sacc[m] cols=q(c), rows=keys m*16 + hh*4 + j
        f32x4 sacc[4];
        __builtin_amdgcn_s_setprio(1);
        #pragma unroll
        for (int m = 0; m < 4; m++) {
            const int row = m * 16 + c;
            const int sw = (row & 7) << 4;
            bf16x8 kf0 = *(const bf16x8*)(kb + row * 128 + ((hh * 16) ^ sw));
            bf16x8 kf1 = *(const bf16x8*)(kb + row * 128 + ((64 + hh * 16) ^ sw));
            f32x4 z = (f32x4){0.f, 0.f, 0.f, 0.f};
            z = __builtin_amdgcn_mfma_f32_16x16x32_bf16(kf0, qf0, z, 0, 0, 0);
            sacc[m] = __builtin_amdgcn_mfma_f32_16x16x32_bf16(kf1, qf1, z, 0, 0, 0);
        }
        __builtin_amdgcn_s_setprio(0);

        // softmax on raw scores; scale folded into exp2 constant
        const bool diag = (kt == qb);
        float s[16];
        float pmax = -3.0e38f;
        #pragma unroll
        for (int m = 0; m < 4; m++)
            #pragma unroll
            for (int j = 0; j < 4; j++) {
                float sv = sacc[m][j];
                if (diag) {
                    int klocal = m * 16 + hh * 4 + j;
                    if (klocal > w * 16 + c) sv = -1e30f;
                }
                s[m * 4 + j] = sv;
                pmax = fmaxf(pmax, sv);
            }
        pmax = fmaxf(pmax, __shfl_xor(pmax, 16));
        pmax = fmaxf(pmax, __shfl_xor(pmax, 32));

        // defer-max: rescale only if some row's max grew by > 64 raw (=8 scaled)
        if (!__all(pmax <= m_run + 64.0f)) {
            const float mnew = fmaxf(m_run, pmax);
            const float alpha = exp2f((m_run - mnew) * Cc);
            m_run = mnew;
            l *= alpha;
            const float a0 = __shfl(alpha, hh * 4 + 0);
            const float a1 = __shfl(alpha, hh * 4 + 1);
            const float a2 = __shfl(alpha, hh * 4 + 2);
            const float a3 = __shfl(alpha, hh * 4 + 3);
            #pragma unroll
            for (int n = 0; n < 4; n++) {
                acc_o[n][0] *= a0; acc_o[n][1] *= a1;
                acc_o[n][2] *= a2; acc_o[n][3] *= a3;
            }
        }
        const float mc = m_run * Cc;
        float p[16];
        #pragma unroll
        for (int i = 0; i < 16; i++) {
            p[i] = exp2f(fmaf(s[i], Cc, -mc));
            l += p[i];
        }

        // pack P -> bf16, per-wave swizzled LDS
        {
            char* pb = (char*)&Pls[w][0] + c * 128;
            const int swp = (c & 7) << 4;
            #pragma unroll
            for (int m = 0; m < 4; m++) {
                unsigned int lo = (unsigned int)f2bf(p[m * 4 + 0]) |
                                  ((unsigned int)f2bf(p[m * 4 + 1]) << 16);
                unsigned int hi = (unsigned int)f2bf(p[m * 4 + 2]) |
                                  ((unsigned int)f2bf(p[m * 4 + 3]) << 16);
                uint2 u; u.x = lo; u.y = hi;
                *(uint2*)(pb + ((m * 32 + hh * 8) ^ swp)) = u;
            }
        }

        // PV: out[q][d], A = P, B = Vt
        {
            const char* pb = (const char*)&Pls[w][0] + c * 128;
            const int swp = (c & 7) << 4;
            bf16x8 pf0 = *(const bf16x8*)(pb + ((hh * 16) ^ swp));
            bf16x8 pf1 = *(const bf16x8*)(pb + ((64 + hh * 16) ^ swp));
            __builtin_amdgcn_s_setprio(1);
            #pragma unroll
            for (int n = 0; n < 4; n++) {
                const int row = n * 16 + c;
                const int sw = (row & 7) << 4;
                bf16x8 vf0 = *(const bf16x8*)(vb + row * 128 + ((hh * 16) ^ sw));
                bf16x8 vf1 = *(const bf16x8*)(vb + row * 128 + ((64 + hh * 16) ^ sw));
                acc_o[n] = __builtin_amdgcn_mfma_f32_16x16x32_bf16(pf0, vf0, acc_o[n], 0, 0, 0);
                acc_o[n] = __builtin_amdgcn_mfma_f32_16x16x32_bf16(pf1, vf1, acc_o[n], 0, 0, 0);
            }
            __builtin_amdgcn_s_setprio(0);
        }
        __syncthreads();
    }
    #undef STAGE

    // final normalization + store
    l += __shfl_xor(l, 16);
    l += __shfl_xor(l, 32);
    const float linv = 1.f / l;
    const float li0 = __shfl(linv, hh * 4 + 0);
    const float li1 = __shfl(linv, hh * 4 + 1);
    const float li2 = __shfl(linv, hh * 4 + 2);
    const float li3 = __shfl(linv, hh * 4 + 3);
    const size_t orow0 = (size_t)(b * SEQ + qb * 64 + w * 16 + hh * 4);
    #pragma unroll
    for (int n = 0; n < 4; n++) {
        const int col = h * HDIM + n * 16 + c;
        a_out[(orow0 + 0) * NSTATE + col] = f2bf(acc_o[n][0] * li0);
        a_out[(orow0 + 1) * NSTATE + col] = f2bf(acc_o[n][1] * li1);
        a_out[(orow0 + 2) * NSTATE + col] = f2bf(acc_o[n][2] * li2);
        a_out[(orow0 + 3) * NSTATE + col] = f2bf(acc_o[n][3] * li3);
    }
}

extern "C" void kernel_launch(void* const* d_in, const int* in_sizes, int n_in,
                              void* d_out, int out_size, void* d_ws, size_t ws_size,
                              hipStream_t stream)
{
    const float* x   = (const float*)d_in[0];
    const float* w_c = (const float*)d_in[1];
    const float* b_c = (const float*)d_in[2];
    const float* w_p = (const float*)d_in[3];
    const float* b_p = (const float*)d_in[4];
    float* out = (float*)d_out;

    const int M = BATCH * SEQ;   // 4096

    char* ws = (char*)d_ws;
    unsigned short* qkvbf = (unsigned short*)ws;                          // 25165824 B
    unsigned short* vt    = (unsigned short*)(ws + 25165824);             //  8388608 B
    unsigned short* xbf   = (unsigned short*)(ws + 25165824 + 8388608);   //  8388608 B (reused as attn_out)
    unsigned short* wcT   = (unsigned short*)(ws + 25165824 + 2*8388608); //  6291456 B
    unsigned short* wpT   = (unsigned short*)(ws + 25165824 + 2*8388608 + 6291456); // 2097152 B

    // fused prep: cast x + transpose-cast w_c, w_p
    prep_kernel<<<5120, 256, 0, stream>>>(x, w_c, w_p, xbf, wcT, wpT);

    // 1) QKV projection -> bf16 qkv
    gemm_bf16<true><<<dim3(M / 128, 3 * NSTATE / 128), 256, 0, stream>>>(
        xbf, wcT, b_c, qkvbf, M, 3 * NSTATE, NX);

    // 1b) transpose V -> vt
    vtrans_kernel<<<dim3(SEQ / 64, BATCH * NHEAD), 256, 0, stream>>>(qkvbf, vt);

    // 2) MFMA flash attention -> bf16 attn_out (reuses xbf)
    attn_mfma<<<dim3(SEQ / 64, NHEAD, BATCH), 256, 0, stream>>>(qkvbf, vt, xbf);

    // 3) output projection -> fp32 d_out
    gemm_bf16<false><<<dim3(M / 128, NSTATE / 128), 256, 0, stream>>>(
        xbf, wpT, b_p, out, M, NSTATE, NX);
}

// Round 6
// 204.059 us; speedup vs baseline: 15.6587x; 1.1413x over previous
//
#include <hip/hip_runtime.h>
#include <math.h>

#define BATCH 2
#define SEQ 2048
#define NX 1024
#define NSTATE 1024
#define NHEAD 16
#define HDIM 64
#define QKV_LD (3*NSTATE)

typedef __attribute__((ext_vector_type(4))) float f32x4;
typedef __attribute__((ext_vector_type(8))) short bf16x8;

__device__ __forceinline__ unsigned short f2bf(float x) {
    unsigned int u = __float_as_uint(x);
    u = (u + 0x7FFFu + ((u >> 16) & 1u)) >> 16;
    return (unsigned short)u;
}

__device__ __forceinline__ unsigned int cvtpk_bf16(float a, float b) {
    unsigned int r;
    asm("v_cvt_pk_bf16_f32 %0, %1, %2" : "=v"(r) : "v"(a), "v"(b));
    return r;
}

#define GLL(src, dst) __builtin_amdgcn_global_load_lds( \
    (const __attribute__((address_space(1))) void*)(src), \
    (__attribute__((address_space(3))) void*)(dst), 16, 0, 0)

// Fused prep: [0,4096) cast x -> bf16; [4096,4864) transpose-cast w_c;
// [4864,5120) transpose-cast w_p.
__global__ __launch_bounds__(256) void prep_kernel(
    const float* __restrict__ x, const float* __restrict__ w_c,
    const float* __restrict__ w_p,
    unsigned short* __restrict__ xbf, unsigned short* __restrict__ wcT,
    unsigned short* __restrict__ wpT)
{
    const int bx = blockIdx.x;
    const int t = threadIdx.x;
    if (bx < 4096) {
        int i = bx * 256 + t;
        float4 v = ((const float4*)x)[i];
        ushort4 o;
        o.x = f2bf(v.x); o.y = f2bf(v.y); o.z = f2bf(v.z); o.w = f2bf(v.w);
        ((ushort4*)xbf)[i] = o;
        return;
    }
    __shared__ float tile[64][65];
    const float* in;
    unsigned short* out;
    int R, C, c0, r0;
    if (bx < 4096 + 768) {
        int idx = bx - 4096;
        in = w_c; out = wcT; R = NX; C = 3 * NSTATE;
        c0 = (idx % 48) * 64; r0 = (idx / 48) * 64;
    } else {
        int idx = bx - 4864;
        in = w_p; out = wpT; R = NX; C = NSTATE;
        c0 = (idx % 16) * 64; r0 = (idx / 16) * 64;
    }
    const int cc = t & 63;
    const int rb = t >> 6;
    #pragma unroll
    for (int i = 0; i < 16; i++) {
        int rr = rb + i * 4;
        tile[rr][cc] = in[(size_t)(r0 + rr) * C + c0 + cc];
    }
    __syncthreads();
    #pragma unroll
    for (int i = 0; i < 16; i++) {
        int rr = rb + i * 4;
        out[(size_t)(c0 + rr) * R + r0 + cc] = f2bf(tile[cc][rr]);
    }
}

// V-part of qkv (bf16) -> vt[(b*16+h)*64+d][s]  (bf16)
__global__ __launch_bounds__(256) void vtrans_kernel(
    const unsigned short* __restrict__ qkv, unsigned short* __restrict__ vt)
{
    __shared__ unsigned short t[64][72];
    const int s0 = blockIdx.x * 64;
    const int bh = blockIdx.y;
    const int b = bh >> 4, h = bh & 15;
    const int r = threadIdx.x >> 2;
    const int cg = (threadIdx.x & 3) * 16;
    const unsigned short* src = qkv + (size_t)(b * SEQ + s0 + r) * QKV_LD
                                + 2 * NSTATE + h * HDIM + cg;
    *(bf16x8*)&t[r][cg]     = *(const bf16x8*)src;
    *(bf16x8*)&t[r][cg + 8] = *(const bf16x8*)(src + 8);
    __syncthreads();
    unsigned short tmp[16];
    #pragma unroll
    for (int i = 0; i < 16; i++) tmp[i] = t[cg + i][r];
    unsigned short* dst = vt + (size_t)(bh * 64 + r) * SEQ + s0 + cg;
    *(bf16x8*)dst       = ((const bf16x8*)tmp)[0];
    *(bf16x8*)(dst + 8) = ((const bf16x8*)tmp)[1];
}

// C[M,N] = A[M,K](bf16) @ BT[N,K]^T(bf16) + bias; out fp32 or bf16.
template<bool BF16_OUT>
__global__ __launch_bounds__(256) void gemm_bf16(
    const unsigned short* __restrict__ A,
    const unsigned short* __restrict__ BT,
    const float* __restrict__ bias,
    void* __restrict__ Cv, int M, int N, int K)
{
    __shared__ unsigned short Als[128 * 32];
    __shared__ unsigned short Bls[128 * 32];
    const int tid = threadIdx.x;
    const int wave = tid >> 6, lane = tid & 63;
    const int bm = blockIdx.x * 128, bn = blockIdx.y * 128;
    const int wr = (wave >> 1) * 64, wc = (wave & 1) * 64;

    f32x4 acc[4][4];
    #pragma unroll
    for (int m = 0; m < 4; m++)
        #pragma unroll
        for (int n = 0; n < 4; n++)
            acc[m][n] = (f32x4){0.f, 0.f, 0.f, 0.f};

    const int arow = tid >> 2;
    const int ac8 = (tid & 3) * 8;
    char* alds0 = (char*)Als + wave * 1024;
    char* blds0 = (char*)Bls + wave * 1024;
    const int fr = lane & 15, kq = (lane >> 4) * 8;

    for (int k0 = 0; k0 < K; k0 += 32) {
        const unsigned short* ga0 = A  + (size_t)(bm + arow) * K + k0 + ac8;
        const unsigned short* gb0 = BT + (size_t)(bn + arow) * K + k0 + ac8;
        GLL(ga0, alds0);
        GLL(ga0 + (size_t)64 * K, alds0 + 4096);
        GLL(gb0, blds0);
        GLL(gb0 + (size_t)64 * K, blds0 + 4096);
        __syncthreads();

        bf16x8 af[4], bfr[4];
        #pragma unroll
        for (int m = 0; m < 4; m++)
            af[m] = *(const bf16x8*)&Als[(wr + m * 16 + fr) * 32 + kq];
        #pragma unroll
        for (int n = 0; n < 4; n++)
            bfr[n] = *(const bf16x8*)&Bls[(wc + n * 16 + fr) * 32 + kq];
        #pragma unroll
        for (int m = 0; m < 4; m++)
            #pragma unroll
            for (int n = 0; n < 4; n++)
                acc[m][n] = __builtin_amdgcn_mfma_f32_16x16x32_bf16(
                    af[m], bfr[n], acc[m][n], 0, 0, 0);
        __syncthreads();
    }

    const int cr = (lane >> 4) * 4;
    const int ccol = lane & 15;
    #pragma unroll
    for (int m = 0; m < 4; m++) {
        const int row = bm + wr + m * 16 + cr;
        #pragma unroll
        for (int n = 0; n < 4; n++) {
            const int col = bn + wc + n * 16 + ccol;
            const float bv = bias[col];
            #pragma unroll
            for (int j = 0; j < 4; j++) {
                float v = acc[m][n][j] + bv;
                if (BF16_OUT)
                    ((unsigned short*)Cv)[(size_t)(row + j) * N + col] = f2bf(v);
                else
                    ((float*)Cv)[(size_t)(row + j) * N + col] = v;
            }
        }
    }
}

// MFMA flash attention, double-buffered K/V staging, balanced qb pairing:
// block bx processes q-tiles (31-bx) then (bx) -> every block = 33 k-tiles.
// 4 waves x 16 q-rows; KV tiles of 64. Swapped QK^T. grid (16, H, B).
__global__ __launch_bounds__(256) void attn_mfma(
    const unsigned short* __restrict__ qkv,
    const unsigned short* __restrict__ vt,
    unsigned short* __restrict__ a_out)
{
    const int bx = blockIdx.x;
    const int h = blockIdx.y, b = blockIdx.z;
    const int tid = threadIdx.x;
    const int w = tid >> 6, lane = tid & 63;
    const int c = lane & 15, hh = lane >> 4;

    __shared__ unsigned short Kls[2 * 64 * 64];
    __shared__ unsigned short Vls[2 * 64 * 64];
    __shared__ unsigned short Pls[4][16 * 64];

    const float Cc = 0.18033688f;          // 0.125 * log2(e)

    // staging geometry: LDS byte o = tid*16 (+4096); row r = o>>7; swizzled src col
    const int o0 = tid * 16;
    const int r0 = o0 >> 7, sc0 = (o0 & 127) ^ ((r0 & 7) << 4);
    const int o1 = 4096 + tid * 16;
    const int r1 = o1 >> 7, sc1 = (o1 & 127) ^ ((r1 & 7) << 4);

    char* kld = (char*)Kls + w * 1024;
    char* vld = (char*)Vls + w * 1024;
    const char* gkbase = (const char*)(qkv + (size_t)b * SEQ * QKV_LD + NSTATE + h * HDIM);
    const char* gvbase = (const char*)(vt + (size_t)(b * NHEAD + h) * HDIM * SEQ);

    #define STAGE(kt_, buf_) do { \
        const char* gk = gkbase + (size_t)(kt_) * 64 * 6144; \
        const char* gv = gvbase + (size_t)(kt_) * 128; \
        char* kd = kld + (buf_) * 8192; \
        char* vd = vld + (buf_) * 8192; \
        GLL(gk + (size_t)r0 * 6144 + sc0, kd); \
        GLL(gk + (size_t)r1 * 6144 + sc1, kd + 4096); \
        GLL(gv + (size_t)r0 * 4096 + sc0, vd); \
        GLL(gv + (size_t)r1 * 4096 + sc1, vd + 4096); \
    } while (0)

    for (int phase = 0; phase < 2; phase++) {
        const int qb = phase ? bx : (31 - bx);

        const size_t qrow = (size_t)(b * SEQ + qb * 64 + w * 16 + c);
        const unsigned short* qp = qkv + qrow * QKV_LD + h * HDIM;
        bf16x8 qf0 = *(const bf16x8*)(qp + hh * 8);
        bf16x8 qf1 = *(const bf16x8*)(qp + 32 + hh * 8);

        f32x4 acc_o[4];
        #pragma unroll
        for (int n = 0; n < 4; n++) acc_o[n] = (f32x4){0.f, 0.f, 0.f, 0.f};
        float m_run = -1e30f, l = 0.f;

        const int nkt = qb + 1;
        STAGE(0, 0);
        __syncthreads();

        for (int kt = 0; kt < nkt; kt++) {
            const int cur = kt & 1;
            if (kt + 1 < nkt) STAGE(kt + 1, cur ^ 1);

            const char* kb = (const char*)Kls + cur * 8192;
            const char* vb = (const char*)Vls + cur * 8192;

            // QK^T (swapped): sacc[m] cols=q(c), rows=keys m*16 + hh*4 + j
            f32x4 sacc[4];
            __builtin_amdgcn_s_setprio(1);
            #pragma unroll
            for (int m = 0; m < 4; m++) {
                const int row = m * 16 + c;
                const int sw = (row & 7) << 4;
                bf16x8 kf0 = *(const bf16x8*)(kb + row * 128 + ((hh * 16) ^ sw));
                bf16x8 kf1 = *(const bf16x8*)(kb + row * 128 + ((64 + hh * 16) ^ sw));
                f32x4 z = (f32x4){0.f, 0.f, 0.f, 0.f};
                z = __builtin_amdgcn_mfma_f32_16x16x32_bf16(kf0, qf0, z, 0, 0, 0);
                sacc[m] = __builtin_amdgcn_mfma_f32_16x16x32_bf16(kf1, qf1, z, 0, 0, 0);
            }
            __builtin_amdgcn_s_setprio(0);

            // softmax on raw scores; scale folded into exp2 constant
            const bool diag = (kt == qb);
            float s[16];
            #pragma unroll
            for (int m = 0; m < 4; m++)
                #pragma unroll
                for (int j = 0; j < 4; j++) {
                    float sv = sacc[m][j];
                    if (diag) {
                        int klocal = m * 16 + hh * 4 + j;
                        if (klocal > w * 16 + c) sv = -1e30f;
                    }
                    s[m * 4 + j] = sv;
                }
            // tree max over 16
            float x0 = fmaxf(s[0], s[1]),  x1 = fmaxf(s[2], s[3]);
            float x2 = fmaxf(s[4], s[5]),  x3 = fmaxf(s[6], s[7]);
            float x4 = fmaxf(s[8], s[9]),  x5 = fmaxf(s[10], s[11]);
            float x6 = fmaxf(s[12], s[13]), x7 = fmaxf(s[14], s[15]);
            float y0 = fmaxf(x0, x1), y1 = fmaxf(x2, x3);
            float y2 = fmaxf(x4, x5), y3 = fmaxf(x6, x7);
            float pmax = fmaxf(fmaxf(y0, y1), fmaxf(y2, y3));
            pmax = fmaxf(pmax, __shfl_xor(pmax, 16));
            pmax = fmaxf(pmax, __shfl_xor(pmax, 32));

            // defer-max: rescale only if some row's max grew by > 64 raw (=8 scaled)
            if (!__all(pmax <= m_run + 64.0f)) {
                const float mnew = fmaxf(m_run, pmax);
                const float alpha = exp2f((m_run - mnew) * Cc);
                m_run = mnew;
                l *= alpha;
                const float a0 = __shfl(alpha, hh * 4 + 0);
                const float a1 = __shfl(alpha, hh * 4 + 1);
                const float a2 = __shfl(alpha, hh * 4 + 2);
                const float a3 = __shfl(alpha, hh * 4 + 3);
                #pragma unroll
                for (int n = 0; n < 4; n++) {
                    acc_o[n][0] *= a0; acc_o[n][1] *= a1;
                    acc_o[n][2] *= a2; acc_o[n][3] *= a3;
                }
            }
            const float mc = m_run * Cc;
            float p[16];
            #pragma unroll
            for (int i = 0; i < 16; i++)
                p[i] = exp2f(fmaf(s[i], Cc, -mc));
            // tree sum into l
            {
                float a0 = p[0] + p[1],  a1 = p[2] + p[3];
                float a2 = p[4] + p[5],  a3 = p[6] + p[7];
                float a4 = p[8] + p[9],  a5 = p[10] + p[11];
                float a6 = p[12] + p[13], a7 = p[14] + p[15];
                float b0 = a0 + a1, b1 = a2 + a3, b2 = a4 + a5, b3 = a6 + a7;
                l += (b0 + b1) + (b2 + b3);
            }

            // pack P -> bf16 via v_cvt_pk_bf16_f32, per-wave swizzled LDS
            {
                char* pb = (char*)&Pls[w][0] + c * 128;
                const int swp = (c & 7) << 4;
                #pragma unroll
                for (int m = 0; m < 4; m++) {
                    uint2 u;
                    u.x = cvtpk_bf16(p[m * 4 + 0], p[m * 4 + 1]);
                    u.y = cvtpk_bf16(p[m * 4 + 2], p[m * 4 + 3]);
                    *(uint2*)(pb + ((m * 32 + hh * 8) ^ swp)) = u;
                }
            }

            // PV: out[q][d], A = P, B = Vt
            {
                const char* pb = (const char*)&Pls[w][0] + c * 128;
                const int swp = (c & 7) << 4;
                bf16x8 pf0 = *(const bf16x8*)(pb + ((hh * 16) ^ swp));
                bf16x8 pf1 = *(const bf16x8*)(pb + ((64 + hh * 16) ^ swp));
                __builtin_amdgcn_s_setprio(1);
                #pragma unroll
                for (int n = 0; n < 4; n++) {
                    const int row = n * 16 + c;
                    const int sw = (row & 7) << 4;
                    bf16x8 vf0 = *(const bf16x8*)(vb + row * 128 + ((hh * 16) ^ sw));
                    bf16x8 vf1 = *(const bf16x8*)(vb + row * 128 + ((64 + hh * 16) ^ sw));
                    acc_o[n] = __builtin_amdgcn_mfma_f32_16x16x32_bf16(pf0, vf0, acc_o[n], 0, 0, 0);
                    acc_o[n] = __builtin_amdgcn_mfma_f32_16x16x32_bf16(pf1, vf1, acc_o[n], 0, 0, 0);
                }
                __builtin_amdgcn_s_setprio(0);
            }
            __syncthreads();
        }

        // final normalization + store
        l += __shfl_xor(l, 16);
        l += __shfl_xor(l, 32);
        const float linv = 1.f / l;
        const float li0 = __shfl(linv, hh * 4 + 0);
        const float li1 = __shfl(linv, hh * 4 + 1);
        const float li2 = __shfl(linv, hh * 4 + 2);
        const float li3 = __shfl(linv, hh * 4 + 3);
        const size_t orow0 = (size_t)(b * SEQ + qb * 64 + w * 16 + hh * 4);
        #pragma unroll
        for (int n = 0; n < 4; n++) {
            const int col = h * HDIM + n * 16 + c;
            a_out[(orow0 + 0) * NSTATE + col] = f2bf(acc_o[n][0] * li0);
            a_out[(orow0 + 1) * NSTATE + col] = f2bf(acc_o[n][1] * li1);
            a_out[(orow0 + 2) * NSTATE + col] = f2bf(acc_o[n][2] * li2);
            a_out[(orow0 + 3) * NSTATE + col] = f2bf(acc_o[n][3] * li3);
        }
    }
    #undef STAGE
}

extern "C" void kernel_launch(void* const* d_in, const int* in_sizes, int n_in,
                              void* d_out, int out_size, void* d_ws, size_t ws_size,
                              hipStream_t stream)
{
    const float* x   = (const float*)d_in[0];
    const float* w_c = (const float*)d_in[1];
    const float* b_c = (const float*)d_in[2];
    const float* w_p = (const float*)d_in[3];
    const float* b_p = (const float*)d_in[4];
    float* out = (float*)d_out;

    const int M = BATCH * SEQ;   // 4096

    char* ws = (char*)d_ws;
    unsigned short* qkvbf = (unsigned short*)ws;                          // 25165824 B
    unsigned short* vt    = (unsigned short*)(ws + 25165824);             //  8388608 B
    unsigned short* xbf   = (unsigned short*)(ws + 25165824 + 8388608);   //  8388608 B (reused as attn_out)
    unsigned short* wcT   = (unsigned short*)(ws + 25165824 + 2*8388608); //  6291456 B
    unsigned short* wpT   = (unsigned short*)(ws + 25165824 + 2*8388608 + 6291456); // 2097152 B

    // fused prep: cast x + transpose-cast w_c, w_p
    prep_kernel<<<5120, 256, 0, stream>>>(x, w_c, w_p, xbf, wcT, wpT);

    // 1) QKV projection -> bf16 qkv
    gemm_bf16<true><<<dim3(M / 128, 3 * NSTATE / 128), 256, 0, stream>>>(
        xbf, wcT, b_c, qkvbf, M, 3 * NSTATE, NX);

    // 1b) transpose V -> vt
    vtrans_kernel<<<dim3(SEQ / 64, BATCH * NHEAD), 256, 0, stream>>>(qkvbf, vt);

    // 2) MFMA flash attention (balanced qb pairing) -> bf16 attn_out (reuses xbf)
    attn_mfma<<<dim3(16, NHEAD, BATCH), 256, 0, stream>>>(qkvbf, vt, xbf);

    // 3) output projection -> fp32 d_out
    gemm_bf16<false><<<dim3(M / 128, NSTATE / 128), 256, 0, stream>>>(
        xbf, wpT, b_p, out, M, NSTATE, NX);
}